// Round 1
// baseline (141.566 us; speedup 1.0000x reference)
//
#include <hip/hip_runtime.h>
#include <math.h>

#define NROWS 131072
#define NCLS 1000
static constexpr float TAU_F = 1e-5f;

// ws layout:
// [0,     4096)  hist   (uint32 x 1024)   -- zeroed each call
// [4096,  8192)  colsum (float  x 1024)   -- zeroed each call
// [8192,  8200)  acc    (double)          -- zeroed each call
// [8200,  8204)  S      (float)           -- written by bias_kernel
// [8448, 12544)  bias   (float  x 1024)   -- written by bias_kernel
// [12544, 12544 + NROWS*4)  pt (float per row)

__global__ __launch_bounds__(256) void colsum_kernel(const float* __restrict__ conf,
                                                     float* __restrict__ colsum) {
    int j = blockIdx.x * 256 + threadIdx.x;
    if (j >= NCLS) return;
    int r0 = blockIdx.y * 125;           // 8 y-blocks x 125 rows = 1000
    int r1 = r0 + 125;
    float s = 0.f;
    for (int i = r0; i < r1; ++i) s += conf[(size_t)i * NCLS + j];
    atomicAdd(&colsum[j], s);
}

// one wave (64 lanes) per row: online softmax + argmax + target gather
__global__ __launch_bounds__(256) void row_kernel(const float* __restrict__ logits,
                                                  const int* __restrict__ targets,
                                                  float* __restrict__ pt,
                                                  unsigned* __restrict__ hist) {
    int gid  = blockIdx.x * 256 + threadIdx.x;
    int row  = gid >> 6;
    int lane = threadIdx.x & 63;
    if (row >= NROWS) return;
    const float* rp = logits + (size_t)row * NCLS;
    int tgt = targets[row];

    float m = -INFINITY, s = 0.f, lt = -INFINITY;
    int amax = 0;
    for (int base = lane * 4; base < NCLS; base += 256) {
        const float4 v = *reinterpret_cast<const float4*>(rp + base);
        float vv[4] = {v.x, v.y, v.z, v.w};
#pragma unroll
        for (int k = 0; k < 4; ++k) {
            float val = vv[k];
            int col = base + k;
            bool gt = val > m;
            float nm = gt ? val : m;
            s = s * __expf(m - nm) + __expf(val - nm);
            if (gt) amax = col;
            m = nm;
            if (col == tgt) lt = val;
        }
    }
#pragma unroll
    for (int off = 32; off; off >>= 1) {
        float m2 = __shfl_xor(m, off);
        float s2 = __shfl_xor(s, off);
        int   a2 = __shfl_xor(amax, off);
        float l2 = __shfl_xor(lt, off);
        float nm = fmaxf(m, m2);
        s = s * __expf(m - nm) + s2 * __expf(m2 - nm);
        if (m2 > m || (m2 == m && a2 < amax)) amax = a2;  // first-occurrence tie rule
        m = nm;
        lt = fmaxf(lt, l2);
    }
    if (lane == 0) {
        pt[row] = __expf(lt - m) / s;
        atomicAdd(&hist[amax], 1u);
    }
}

__global__ __launch_bounds__(1024) void bias_kernel(const float* __restrict__ colsum,
                                                    const unsigned* __restrict__ hist,
                                                    float* __restrict__ bias,
                                                    float* __restrict__ Sout) {
    __shared__ float red[1024];
    int j = threadIdx.x;
    float b = 0.f;
    if (j < NCLS) {
        float cs = colsum[j] + (float)hist[j];
        if (cs == 0.f) cs = 1e-8f;
        b = TAU_F * powf(cs, -0.25f);
        bias[j] = b;
    }
    red[j] = b;
    __syncthreads();
    for (int off = 512; off; off >>= 1) {
        if (j < off) red[j] += red[j + off];
        __syncthreads();
    }
    if (j == 0) Sout[0] = red[0];
}

__global__ __launch_bounds__(256) void loss_kernel(const float* __restrict__ pt,
                                                   const int* __restrict__ targets,
                                                   const float* __restrict__ bias,
                                                   double* __restrict__ acc) {
    __shared__ double red[256];
    int i = blockIdx.x * 256 + threadIdx.x;
    double v = 0.0;
    if (i < NROWS) {
        float y = pt[i] - bias[targets[i]];
        v = -(double)__logf(y);
    }
    red[threadIdx.x] = v;
    __syncthreads();
    for (int off = 128; off; off >>= 1) {
        if (threadIdx.x < off) red[threadIdx.x] += red[threadIdx.x + off];
        __syncthreads();
    }
    if (threadIdx.x == 0) atomicAdd(acc, red[0]);
}

__global__ void final_kernel(const double* __restrict__ acc,
                             const float* __restrict__ Sp,
                             float* __restrict__ out) {
    double S = (double)Sp[0];
    out[0] = (float)(acc[0] / (double)NROWS + log(1.0 - S));
}

extern "C" void kernel_launch(void* const* d_in, const int* in_sizes, int n_in,
                              void* d_out, int out_size, void* d_ws, size_t ws_size,
                              hipStream_t stream) {
    const float* logits  = (const float*)d_in[0];
    const int*   targets = (const int*)d_in[1];
    const float* conf    = (const float*)d_in[2];

    char* ws = (char*)d_ws;
    unsigned* hist   = (unsigned*)(ws + 0);
    float*    colsum = (float*)(ws + 4096);
    double*   acc    = (double*)(ws + 8192);
    float*    Sp     = (float*)(ws + 8200);
    float*    bias   = (float*)(ws + 8448);
    float*    pt     = (float*)(ws + 12544);

    hipMemsetAsync(ws, 0, 8208, stream);  // hist + colsum + acc

    dim3 gA(4, 8);
    colsum_kernel<<<gA, 256, 0, stream>>>(conf, colsum);
    row_kernel<<<NROWS / 4, 256, 0, stream>>>(logits, targets, pt, hist);
    bias_kernel<<<1, 1024, 0, stream>>>(colsum, hist, bias, Sp);
    loss_kernel<<<(NROWS + 255) / 256, 256, 0, stream>>>(pt, targets, bias, acc);
    final_kernel<<<1, 1, 0, stream>>>(acc, Sp, (float*)d_out);
}

// Round 2
// 124.093 us; speedup vs baseline: 1.1408x; 1.1408x over previous
//
#include <hip/hip_runtime.h>
#include <math.h>

#define NROWS 131072
#define NCLS 1000
#define CSBLOCKS 500                 // colsum helper blocks (front of grid)
#define ROWBLOCKS (NROWS / 4)        // 4 rows (waves) per 256-thread block
static constexpr float TAU_F = 1e-5f;

// ws layout:
// [0,     4096)  hist   (uint32 x 1024)   -- zeroed each call
// [4096,  8192)  colsum (float  x 1024)   -- zeroed each call
// [8192,  8200)  acc    (double)          -- zeroed each call
// [8200,  8204)  S      (float)           -- written by bias_kernel
// [8448, 12544)  bias   (float  x 1024)   -- written by bias_kernel
// [12544, 12544 + NROWS*4)  pt (float per row)

__global__ __launch_bounds__(256) void main_kernel(const float* __restrict__ logits,
                                                   const int* __restrict__ targets,
                                                   const float* __restrict__ conf,
                                                   float* __restrict__ pt,
                                                   unsigned* __restrict__ hist,
                                                   float* __restrict__ colsum) {
    if (blockIdx.x < CSBLOCKS) {
        // ---- colsum of conf_N: 500 blocks, 8 rows x 256 cols each ----
        int bid = blockIdx.x;
        int j  = (bid & 3) * 256 + threadIdx.x;
        int r0 = (bid >> 2) * 8;
        if (j < NCLS) {
            float s = 0.f;
#pragma unroll
            for (int i = 0; i < 8; ++i) s += conf[(size_t)(r0 + i) * NCLS + j];
            atomicAdd(&colsum[j], s);
        }
        return;
    }
    // ---- one wave per row: softmax(target prob) + argmax histogram ----
    int row  = ((blockIdx.x - CSBLOCKS) << 2) + (threadIdx.x >> 6);
    int lane = threadIdx.x & 63;
    const float* rp = logits + (size_t)row * NCLS;
    int tgt = targets[row];

    float v[16];
#pragma unroll
    for (int i = 0; i < 4; ++i) {
        int base = lane * 4 + i * 256;
        if (base < NCLS) {
            const float4 f = *reinterpret_cast<const float4*>(rp + base);
            v[i * 4 + 0] = f.x; v[i * 4 + 1] = f.y;
            v[i * 4 + 2] = f.z; v[i * 4 + 3] = f.w;
        } else {
            v[i * 4 + 0] = v[i * 4 + 1] = v[i * 4 + 2] = v[i * 4 + 3] = -INFINITY;
        }
    }

    // pass 1: lane-local max / first-occurrence argmax / target gather
    float m = -INFINITY, lt = -INFINITY;
    int amax = 0;
#pragma unroll
    for (int i = 0; i < 4; ++i) {
#pragma unroll
        for (int k = 0; k < 4; ++k) {
            int col = lane * 4 + i * 256 + k;   // strictly increasing per lane
            float val = v[i * 4 + k];
            if (val > m) { m = val; amax = col; }
            if (col == tgt) lt = val;
        }
    }
    // wave reduce: max + argmax(first occurrence = lower index on tie) + target
#pragma unroll
    for (int off = 32; off; off >>= 1) {
        float m2 = __shfl_xor(m, off);
        int   a2 = __shfl_xor(amax, off);
        float l2 = __shfl_xor(lt, off);
        if (m2 > m || (m2 == m && a2 < amax)) amax = a2;
        m  = fmaxf(m, m2);
        lt = fmaxf(lt, l2);
    }

    // pass 2: sum of exp (independent chain, one exp per element)
    float s = 0.f;
#pragma unroll
    for (int i = 0; i < 16; ++i) s += __expf(v[i] - m);   // exp(-inf)=0 for pads
#pragma unroll
    for (int off = 32; off; off >>= 1) s += __shfl_xor(s, off);

    if (lane == 0) {
        pt[row] = __expf(lt - m) / s;
        atomicAdd(&hist[amax], 1u);
    }
}

__global__ __launch_bounds__(1024) void bias_kernel(const float* __restrict__ colsum,
                                                    const unsigned* __restrict__ hist,
                                                    float* __restrict__ bias,
                                                    float* __restrict__ Sout) {
    __shared__ float red[1024];
    int j = threadIdx.x;
    float b = 0.f;
    if (j < NCLS) {
        float cs = colsum[j] + (float)hist[j];
        if (cs == 0.f) cs = 1e-8f;
        b = TAU_F * powf(cs, -0.25f);
        bias[j] = b;
    }
    red[j] = b;
    __syncthreads();
    for (int off = 512; off; off >>= 1) {
        if (j < off) red[j] += red[j + off];
        __syncthreads();
    }
    if (j == 0) Sout[0] = red[0];
}

__global__ __launch_bounds__(256) void loss_kernel(const float* __restrict__ pt,
                                                   const int* __restrict__ targets,
                                                   const float* __restrict__ bias,
                                                   double* __restrict__ acc) {
    __shared__ double red[256];
    int i = blockIdx.x * 256 + threadIdx.x;
    double v = 0.0;
    if (i < NROWS) {
        float y = pt[i] - bias[targets[i]];
        v = -(double)__logf(y);
    }
    red[threadIdx.x] = v;
    __syncthreads();
    for (int off = 128; off; off >>= 1) {
        if (threadIdx.x < off) red[threadIdx.x] += red[threadIdx.x + off];
        __syncthreads();
    }
    if (threadIdx.x == 0) atomicAdd(acc, red[0]);
}

__global__ void final_kernel(const double* __restrict__ acc,
                             const float* __restrict__ Sp,
                             float* __restrict__ out) {
    double S = (double)Sp[0];
    out[0] = (float)(acc[0] / (double)NROWS + log(1.0 - S));
}

extern "C" void kernel_launch(void* const* d_in, const int* in_sizes, int n_in,
                              void* d_out, int out_size, void* d_ws, size_t ws_size,
                              hipStream_t stream) {
    const float* logits  = (const float*)d_in[0];
    const int*   targets = (const int*)d_in[1];
    const float* conf    = (const float*)d_in[2];

    char* ws = (char*)d_ws;
    unsigned* hist   = (unsigned*)(ws + 0);
    float*    colsum = (float*)(ws + 4096);
    double*   acc    = (double*)(ws + 8192);
    float*    Sp     = (float*)(ws + 8200);
    float*    bias   = (float*)(ws + 8448);
    float*    pt     = (float*)(ws + 12544);

    hipMemsetAsync(ws, 0, 8208, stream);  // hist + colsum + acc

    main_kernel<<<CSBLOCKS + ROWBLOCKS, 256, 0, stream>>>(logits, targets, conf,
                                                          pt, hist, colsum);
    bias_kernel<<<1, 1024, 0, stream>>>(colsum, hist, bias, Sp);
    loss_kernel<<<(NROWS + 255) / 256, 256, 0, stream>>>(pt, targets, bias, acc);
    final_kernel<<<1, 1, 0, stream>>>(acc, Sp, (float*)d_out);
}